// Round 6
// baseline (623.502 us; speedup 1.0000x reference)
//
#include <hip/hip_runtime.h>
#include <hip/hip_bf16.h>
#include <cmath>

// B,T,D,H = 4096,48,64,128
#define Bb 4096
#define Tt 48
#define Dd 64
#define Hh 128
#define NB 16      // batch rows per block (M of MFMA)
#define NTHR 1024  // 16 waves: gate-pair split -> 64 weight VGPRs/wave -> 4 waves/SIMD

// Raw workgroup barrier WITHOUT the vmcnt(0) drain __syncthreads() implies.
#define BAR_LDS() asm volatile("s_waitcnt lgkmcnt(0)\n\ts_barrier" ::: "memory")

typedef unsigned short ushort_t;
typedef __attribute__((ext_vector_type(8))) short short8;    // 8 bf16 = 4 VGPRs (MFMA A/B frag)
typedef __attribute__((ext_vector_type(4))) float floatx4;   // MFMA C/D frag

#define MFMA __builtin_amdgcn_mfma_f32_16x16x32_bf16

// ---- workspace layout (floats) ----
#define WS_DEN   0     // denoms[48]
#define WS_LOSS  48
#define WS_CNT   49    // block completion counter (zeroed by memset)
#define WS_FRAGS 64    // bf16 frag area starts here (16B aligned)
// frag indices (each frag = 64 lanes x 8 bf16 = 512 ushorts = 1 KB)
#define FR_F 0         // 256 frags: gates  [wcol:8][g:4][ks:8]  K=256 (c_c|m|h)
#define FR_A 256       // 16: W_td_h        [w:8][ks:2]          K=64
#define FR_B 272       // 16: W_hist        [w:4][ks:4]          K=128
#define FR_C 288       // 8 : W_feat masked [w:4][ks:2]          K=64
#define FR_E 296       // 16: W_comb        [w:4][ks:4]          K=128
#define N_FRAGS 312
#define DENOM_BLOCKS (48 * 16)

__device__ __forceinline__ ushort_t f2bf(float x) {   // RNE float->bf16 bits (scalar)
  unsigned int u = __float_as_uint(x);
  u += 0x7fffu + ((u >> 16) & 1u);
  return (ushort_t)(u >> 16);
}
// paired RNE pack -> single v_cvt_pk_bf16_f32 (verified identical absmax, R5)
__device__ __forceinline__ unsigned int pack_bf2(float a, float b) {
  union { __hip_bfloat162 h; unsigned int u; } cv;
  cv.h = __float22bfloat162_rn(make_float2(a, b));
  return cv.u;
}
__device__ __forceinline__ float sigmoidf_(float x) { return 1.0f / (1.0f + __expf(-x)); }
__device__ __forceinline__ float tanhf_(float x) { return 2.0f / (1.0f + __expf(-2.0f * x)) - 1.0f; }

// ---------------- kernel 0: weight-frag packing + denom sums (verified R4/R5) ----------------
__global__ void prep_denom_kernel(const float* __restrict__ W_td_h, const float* __restrict__ W_hist,
                                  const float* __restrict__ W_feat, const float* __restrict__ W_comb,
                                  const float* __restrict__ W_ih, const float* __restrict__ W_hh,
                                  const float* __restrict__ masks, float* __restrict__ ws) {
  int tid = threadIdx.x;              // 256 threads
  if (blockIdx.x < N_FRAGS) {
    int f = blockIdx.x;               // one frag per block, 2 elems per thread
    ushort_t* fb = (ushort_t*)(ws + WS_FRAGS);
    #pragma unroll
    for (int u = 0; u < 2; u++) {
      int e = tid * 2 + u;            // 0..511 = l*8 + j
      int l = e >> 3, j = e & 7;
      int n16 = l & 15;
      int kq = ((l >> 4) << 3) + j;   // quad*8 + j  (0..31)
      float v;
      if (f < 256) {
        int w = f >> 5, g = (f >> 3) & 3, ks = f & 7;
        int n = g * 128 + w * 16 + n16;           // gate row in [512]
        int k = ks * 32 + kq;                     // 0..255: 0-127 -> W_ih, 128-255 -> W_hh
        v = (k < 128) ? W_ih[n * 128 + k] : W_hh[n * 128 + (k - 128)];
      } else if (f < 272) {
        int ff = f - 256, w = ff >> 1, ks = ff & 1;
        int n = w * 16 + n16;                     // 0..127
        v = W_td_h[n * 64 + ks * 32 + kq];
      } else if (f < 288) {
        int ff = f - 272, w = ff >> 2, ks = ff & 3;
        int n = w * 16 + n16;                     // 0..63
        v = W_hist[n * 128 + ks * 32 + kq];
      } else if (f < 296) {
        int ff = f - 288, w = ff >> 1, ks = ff & 1;
        int n = w * 16 + n16;
        int k = ks * 32 + kq;
        v = (n == k) ? 0.0f : W_feat[n * 64 + k];  // zeroed diagonal
      } else {
        int ff = f - 296, w = ff >> 2, ks = ff & 3;
        int n = w * 16 + n16;
        v = W_comb[n * 128 + ks * 32 + kq];       // cols: 0-63 gamma_x, 64-127 m
      }
      fb[f * 512 + e] = f2bf(v);
    }
  } else {
    int blk = blockIdx.x - N_FRAGS;
    int t = blk >> 4;
    int chunk = blk & 15;
    int base = chunk * 256;
    int j = tid & 63;
    int brow = tid >> 6;
    float s = 0.0f;
    for (int i = 0; i < 64; i++) {
      int b = base + i * 4 + brow;
      s += masks[((size_t)b * Tt + t) * Dd + j];
    }
    for (int off = 32; off > 0; off >>= 1) s += __shfl_down(s, off, 64);
    __shared__ float red[4];
    if ((tid & 63) == 0) red[tid >> 6] = s;
    __syncthreads();
    if (tid == 0) atomicAdd(&ws[WS_DEN + t], red[0] + red[1] + red[2] + red[3]);
  }
}

// ---------------- kernel 1: 16-wave gate-split persistent recurrence ----------------
// Wave roles: wcol = w&7 (owns 16 h-cols), gsel = w>>3 (owns gate pair: 0->{i,f}, 1->{g,o}).
// F weights per wave: 16 frags = 64 VGPR (half of the old 8-wave design) -> 4 waves/SIMD.
// B on waves 8-11 (x_h kept in regs), E on 12-15 (alpha via albuf), C on 8-11,
// A + LSTM state + h_dec on waves 0-7 (identical math to verified kernel).
// Gate exchange: waves 8-15 export g,o preacts (fp32) via gobuf; waves 0-7 do LSTM.
// 4 barriers/step: P1 | P2 | P3a | P3b.
__global__ __launch_bounds__(NTHR, 1)
void main_kernel(const float* __restrict__ values, const float* __restrict__ masks,
                 const float* __restrict__ deltas, const float* __restrict__ W_td_x,
                 const float* __restrict__ b_td_h, const float* __restrict__ b_td_x,
                 const float* __restrict__ b_hist, const float* __restrict__ b_feat,
                 const float* __restrict__ b_comb,
                 const float* __restrict__ b_ih, const float* __restrict__ b_hh,
                 float* ws, float* __restrict__ out) {
  __shared__ __align__(16) ushort_t act[16 * 264];   // bf16 [16][256+8]: c_c | m | h_dec
  __shared__ __align__(16) ushort_t dbuf[16 * 72];   // bf16 d(t+1)
  __shared__ __align__(16) ushort_t gxbuf[16 * 72];  // bf16 gamma_x
  __shared__ __align__(16) ushort_t xcbuf[16 * 72];  // bf16 x_c
  __shared__ __align__(16) float xmbuf[16 * 132];    // fp32 interleaved [x,m] pairs
  __shared__ __align__(16) float gobuf[2 * 16 * 132];// fp32 g,o gate preacts (pad 132: 2-way banks)
  __shared__ __align__(16) float albuf[16 * 68];     // fp32 alpha
  __shared__ float sden[48];
  __shared__ float red[16];
  extern __shared__ __align__(16) ushort_t wstage[]; // 40 frags (FR_B..FR_E contiguous) = 40 KB

  int tid = threadIdx.x;
  int w = tid >> 6;            // wave 0..15
  int lane = tid & 63;
  int l15 = lane & 15;
  int quad = lane >> 4;
  int wcol = w & 7;
  int gsel = w >> 3;
  int gA = gsel * 2;           // first owned gate (0 or 2)
  int b0 = blockIdx.x * NB;
  const ushort_t* fb = (const ushort_t*)(ws + WS_FRAGS);

  for (int i = tid; i < 48; i += NTHR) sden[i] = 1.0f / (ws[WS_DEN + i] + 1e-5f);
  // stage B/C/E weight frags to LDS (contiguous FR_B..FR_E = 40 frags)
  for (int i = tid; i < 40 * 512 / 8; i += NTHR)
    *(short8*)(wstage + i * 8) = *(const short8*)(fb + (size_t)FR_B * 512 + i * 8);

  // ---- per-wave F gate-pair frags: 16 = 64 VGPR ----
  short8 wF[16];
  #pragma unroll
  for (int g2 = 0; g2 < 2; g2++)
    #pragma unroll
    for (int ks = 0; ks < 8; ks++)
      wF[g2 * 8 + ks] =
          *(const short8*)(fb + (size_t)(FR_F + wcol * 32 + (gA + g2) * 8 + ks) * 512 + lane * 8);
  short8 wA[2];
  if (w < 8) {
    #pragma unroll
    for (int ks = 0; ks < 2; ks++)
      wA[ks] = *(const short8*)(fb + (size_t)(FR_A + w * 2 + ks) * 512 + lane * 8);
  }

  // ---- biases / columns ----
  int colh = wcol * 16 + l15;                       // 0..127
  float biasFa = b_ih[gA * 128 + colh] + b_hh[gA * 128 + colh];
  float biasFb = b_ih[(gA + 1) * 128 + colh] + b_hh[(gA + 1) * 128 + colh];
  float biasA = (w < 8) ? b_td_h[colh] : 0.0f;
  int colD = (w >= 12) ? (wcol - 4) * 16 + l15 : wcol * 16 + l15;   // 0..63 (w>=8)
  float biasP = 0.0f, biasC = 0.0f;
  if (w >= 12) biasP = b_comb[colD];
  else if (w >= 8) { biasP = b_hist[colD]; biasC = b_feat[colD]; }

  // LDS weight-frag bases (w>=8)
  const ushort_t* wbe_p = wstage + (size_t)((w < 12) ? wcol * 4 : 24 + (wcol - 4) * 4) * 512 + lane * 8;
  const ushort_t* wc_p  = wstage + (size_t)(16 + wcol * 2) * 512 + lane * 8;

  // ---- hoisted bases ----
  int haB = quad * 4 * 264 + 128 + colh;            // h_dec write base (w<8), +r*264
  int off0 = 1 + (b0 + quad * 4) * Tt * Dd + colD;  // imp store base (w 8-11), +r*3072 +t*64

  float c_reg[4] = {0.f, 0.f, 0.f, 0.f};            // LSTM state (w<8)
  float loss_acc = 0.0f;                            // (w 8-11)

  // ---- input staging mapping + prologue (waves 8-15 own the 512 staging slots) ----
  float2 px, pm, pd;
  int lb = 0, li = 0;
  size_t gbase = 0;
  float diag0 = 0, diag1 = 0, btx0 = 0, btx1 = 0;
  if (w >= 8) {
    int e0 = (tid - 512) * 2;
    lb = e0 >> 6; li = e0 & 63;                     // li even
    gbase = ((size_t)(b0 + lb) * Tt) * Dd + li;
    diag0 = W_td_x[li * 64 + li]; diag1 = W_td_x[(li + 1) * 64 + (li + 1)];
    btx0 = b_td_x[li]; btx1 = b_td_x[li + 1];
    px = *(const float2*)(values + gbase);
    pm = *(const float2*)(masks + gbase);
    pd = *(const float2*)(deltas + gbase);
    *(float4*)(&xmbuf[lb * 132 + 2 * li]) = make_float4(px.x, pm.x, px.y, pm.y);
    *(unsigned int*)(&act[lb * 264 + 64 + li]) = pack_bf2(pm.x, pm.y);
    float g0 = __expf(-fmaxf(pd.x * diag0 + btx0, 0.0f));
    float g1 = __expf(-fmaxf(pd.y * diag1 + btx1, 0.0f));
    *(unsigned int*)(&gxbuf[lb * 72 + li]) = pack_bf2(g0, g1);
    size_t g = gbase + Dd;                          // prefetch t=1
    px = *(const float2*)(values + g);
    pm = *(const float2*)(masks + g);
    pd = *(const float2*)(deltas + g);
  }
  {                                                  // zero h_dec region [16][128] (all threads)
    int e = tid;                                     // 0..1023, one u32 each
    *(unsigned int*)(&act[(e >> 6) * 264 + 128 + 2 * (e & 63)]) = 0u;
  }
  __syncthreads();                                   // wstage + staging + sden visible

  for (int t = 0; t < Tt; t++) {
    floatx4 aA = {biasFa, biasFa, biasFa, biasFa};
    floatx4 aB = {biasFb, biasFb, biasFb, biasFb};
    floatx4 accP = {biasP, biasP, biasP, biasP};

    // ---- P1: F.m + F.h (all waves); B (8-11) / E (12-15); x_h epi (8-11), alpha epi (12-15) ----
    short8 mf0 = *(const short8*)(&act[l15 * 264 + 64 + quad * 8]);
    short8 mf1 = *(const short8*)(&act[l15 * 264 + 96 + quad * 8]);
    short8 hf0 = *(const short8*)(&act[l15 * 264 + 128 + quad * 8]);
    short8 hf1 = *(const short8*)(&act[l15 * 264 + 160 + quad * 8]);
    short8 hf2 = *(const short8*)(&act[l15 * 264 + 192 + quad * 8]);
    short8 hf3 = *(const short8*)(&act[l15 * 264 + 224 + quad * 8]);
    if (w >= 8) {
      short8 wb0 = *(const short8*)(wbe_p);
      short8 wb1 = *(const short8*)(wbe_p + 512);
      short8 wb2 = *(const short8*)(wbe_p + 1024);
      short8 wb3 = *(const short8*)(wbe_p + 1536);
      if (w < 12) {                                  // B: x_h = h_dec @ W_hist^T
        accP = MFMA(hf0, wb0, accP, 0, 0, 0);
        accP = MFMA(hf1, wb1, accP, 0, 0, 0);
        accP = MFMA(hf2, wb2, accP, 0, 0, 0);
        accP = MFMA(hf3, wb3, accP, 0, 0, 0);
      } else {                                       // E: alpha = [gamma_x|m] @ W_comb^T
        short8 gx0 = *(const short8*)(&gxbuf[l15 * 72 + quad * 8]);
        short8 gx1 = *(const short8*)(&gxbuf[l15 * 72 + 32 + quad * 8]);
        accP = MFMA(gx0, wb0, accP, 0, 0, 0);
        accP = MFMA(gx1, wb1, accP, 0, 0, 0);
        accP = MFMA(mf0, wb2, accP, 0, 0, 0);
        accP = MFMA(mf1, wb3, accP, 0, 0, 0);
      }
    }
    aA = MFMA(mf0, wF[2],  aA, 0, 0, 0);
    aA = MFMA(mf1, wF[3],  aA, 0, 0, 0);
    aB = MFMA(mf0, wF[10], aB, 0, 0, 0);
    aB = MFMA(mf1, wF[11], aB, 0, 0, 0);
    aA = MFMA(hf0, wF[4],  aA, 0, 0, 0);
    aA = MFMA(hf1, wF[5],  aA, 0, 0, 0);
    aA = MFMA(hf2, wF[6],  aA, 0, 0, 0);
    aA = MFMA(hf3, wF[7],  aA, 0, 0, 0);
    aB = MFMA(hf0, wF[12], aB, 0, 0, 0);
    aB = MFMA(hf1, wF[13], aB, 0, 0, 0);
    aB = MFMA(hf2, wF[14], aB, 0, 0, 0);
    aB = MFMA(hf3, wF[15], aB, 0, 0, 0);
    if (w >= 8 && w < 12) {                          // x_h epilogue: loss1, x_c; x_h stays in accP
      float invden = sden[t];
      float s1 = 0.0f;
      #pragma unroll
      for (int r = 0; r < 4; r++) {
        int m = quad * 4 + r;
        float2 xm = *(const float2*)(&xmbuf[m * 132 + 2 * colD]);
        float xh = accP[r];
        s1 += fabsf(xm.x - xh) * xm.y;
        xcbuf[m * 72 + colD] = f2bf(xm.y * xm.x + (1.0f - xm.y) * xh);
      }
      loss_acc += s1 * invden;
    } else if (w >= 12) {                            // alpha -> albuf
      #pragma unroll
      for (int r = 0; r < 4; r++)
        albuf[(quad * 4 + r) * 68 + colD] = accP[r];
    }
    BAR_LDS();                                       // x_c + alpha staged

    // ---- P2: C + c_c epilogue + imp store (8-11); dbuf staging (8-15) ----
    if (w >= 8 && w < 12) {
      short8 xc0 = *(const short8*)(&xcbuf[l15 * 72 + quad * 8]);
      short8 xc1 = *(const short8*)(&xcbuf[l15 * 72 + 32 + quad * 8]);
      short8 wc0 = *(const short8*)(wc_p);
      short8 wc1 = *(const short8*)(wc_p + 512);
      floatx4 accC = {biasC, biasC, biasC, biasC};
      accC = MFMA(xc0, wc0, accC, 0, 0, 0);
      accC = MFMA(xc1, wc1, accC, 0, 0, 0);
      float invden = sden[t];
      float s23 = 0.0f;
      int tofs = t * 64;
      #pragma unroll
      for (int r = 0; r < 4; r++) {
        int m = quad * 4 + r;
        float2 xm = *(const float2*)(&xmbuf[m * 132 + 2 * colD]);
        float xh = accP[r];
        float zh = accC[r];
        float al = albuf[m * 68 + colD];
        s23 += fabsf(xm.x - zh) * xm.y;              // loss2
        float ch = al * zh + (1.0f - al) * xh;
        s23 += fabsf(xm.x - ch) * xm.y;              // loss3
        float cc = xm.y * xm.x + (1.0f - xm.y) * ch;
        out[off0 + r * 3072 + tofs] = cc;            // imputation store (never drained in-loop)
        act[m * 264 + colD] = f2bf(cc);
      }
      loss_acc += s23 * invden;
    }
    if (w >= 8)
      *(unsigned int*)(&dbuf[lb * 72 + li]) = pack_bf2(pd.x, pd.y);
    BAR_LDS();                                       // c_c + d staged

    // ---- P3a: F.c (all); A MFMA (0-7); gobuf export + input staging (8-15) ----
    short8 cf0 = *(const short8*)(&act[l15 * 264 + quad * 8]);
    short8 cf1 = *(const short8*)(&act[l15 * 264 + 32 + quad * 8]);
    aA = MFMA(cf0, wF[0],  aA, 0, 0, 0);
    aA = MFMA(cf1, wF[1],  aA, 0, 0, 0);
    aB = MFMA(cf0, wF[8],  aB, 0, 0, 0);
    aB = MFMA(cf1, wF[9],  aB, 0, 0, 0);
    floatx4 accA = {biasA, biasA, biasA, biasA};
    if (w < 8) {
      short8 df0 = *(const short8*)(&dbuf[l15 * 72 + quad * 8]);
      short8 df1 = *(const short8*)(&dbuf[l15 * 72 + 32 + quad * 8]);
      accA = MFMA(df0, wA[0], accA, 0, 0, 0);
      accA = MFMA(df1, wA[1], accA, 0, 0, 0);
    } else {
      #pragma unroll
      for (int r = 0; r < 4; r++) {                  // export g,o preacts
        int m = quad * 4 + r;
        gobuf[m * 132 + colh] = aA[r];               // gate g
        gobuf[2112 + m * 132 + colh] = aB[r];        // gate o
      }
      // stage t+1 inputs; prefetch t+2
      *(float4*)(&xmbuf[lb * 132 + 2 * li]) = make_float4(px.x, pm.x, px.y, pm.y);
      *(unsigned int*)(&act[lb * 264 + 64 + li]) = pack_bf2(pm.x, pm.y);
      float g0 = __expf(-fmaxf(pd.x * diag0 + btx0, 0.0f));
      float g1 = __expf(-fmaxf(pd.y * diag1 + btx1, 0.0f));
      *(unsigned int*)(&gxbuf[lb * 72 + li]) = pack_bf2(g0, g1);
      int tn = (t + 2 < Tt) ? (t + 2) : (Tt - 1);
      size_t g = gbase + (size_t)tn * Dd;
      px = *(const float2*)(values + g);
      pm = *(const float2*)(masks + g);
      pd = *(const float2*)(deltas + g);
    }
    BAR_LDS();                                       // gobuf + t+1 inputs staged

    // ---- P3b: LSTM + h_dec(t+1) (waves 0-7) ----
    if (w < 8) {
      #pragma unroll
      for (int r = 0; r < 4; r++) {
        int m = quad * 4 + r;
        float gg = gobuf[m * 132 + colh];
        float og = gobuf[2112 + m * 132 + colh];
        float ig = sigmoidf_(aA[r]);                 // gate i
        float fg = sigmoidf_(aB[r]);                 // gate f
        float g_ = tanhf_(gg);
        float o_ = sigmoidf_(og);
        c_reg[r] = fg * c_reg[r] + ig * g_;
        float h_ = o_ * tanhf_(c_reg[r]);
        float hd = h_ * __expf(-fmaxf(accA[r], 0.0f));  // h_dec(t+1), gamma_h one step ahead
        act[haB + r * 264] = f2bf(hd);
      }
    }
    BAR_LDS();                                       // h_dec staged
  }

  // ---- loss reduction + folded finalization ----
  float s = loss_acc;
  for (int off = 32; off > 0; off >>= 1) s += __shfl_down(s, off, 64);
  if (lane == 0) red[w] = s;
  __syncthreads();
  if (tid == 0) {
    float tot = 0.0f;
    #pragma unroll
    for (int i = 0; i < 16; i++) tot += red[i];
    atomicAdd(&ws[WS_LOSS], tot);
    __threadfence();
    unsigned int done = atomicAdd((unsigned int*)&ws[WS_CNT], 1u);
    if (done == (unsigned int)(gridDim.x - 1)) {
      float lv = atomicAdd(&ws[WS_LOSS], 0.0f);
      out[0] = 0.3f * lv;
    }
  }
}

extern "C" void kernel_launch(void* const* d_in, const int* in_sizes, int n_in,
                              void* d_out, int out_size, void* d_ws, size_t ws_size,
                              hipStream_t stream) {
  const float* values = (const float*)d_in[0];
  const float* masks  = (const float*)d_in[1];
  const float* deltas = (const float*)d_in[2];
  const float* W_td_h = (const float*)d_in[3];
  const float* b_td_h = (const float*)d_in[4];
  const float* W_td_x = (const float*)d_in[5];
  const float* b_td_x = (const float*)d_in[6];
  const float* W_hist = (const float*)d_in[7];
  const float* b_hist = (const float*)d_in[8];
  const float* W_feat = (const float*)d_in[9];
  const float* b_feat = (const float*)d_in[10];
  const float* W_comb = (const float*)d_in[11];
  const float* b_comb = (const float*)d_in[12];
  const float* W_ih   = (const float*)d_in[13];
  const float* W_hh   = (const float*)d_in[14];
  const float* b_ih   = (const float*)d_in[15];
  const float* b_hh   = (const float*)d_in[16];
  float* out = (float*)d_out;
  float* ws  = (float*)d_ws;   // uses 64 + 312*256 floats ≈ 320 KB

  hipMemsetAsync(ws, 0, 64 * sizeof(float), stream);
  prep_denom_kernel<<<dim3(N_FRAGS + DENOM_BLOCKS), dim3(256), 0, stream>>>(
      W_td_h, W_hist, W_feat, W_comb, W_ih, W_hh, masks, ws);
  main_kernel<<<dim3(Bb / NB), dim3(NTHR), 40 * 512 * sizeof(ushort_t), stream>>>(
      values, masks, deltas, W_td_x, b_td_h, b_td_x, b_hist, b_feat,
      b_comb, b_ih, b_hh, ws, out);
}

// Round 7
// 607.984 us; speedup vs baseline: 1.0255x; 1.0255x over previous
//
#include <hip/hip_runtime.h>
#include <cmath>

// B,T,D,H = 4096,48,64,128
#define Bb 4096
#define Tt 48
#define Dd 64
#define Hh 128
#define NB 16      // batch rows per block
#define NTHR 1024  // 16 waves, gate-pair split; hard cap 128 regs/wave -> 4 waves/SIMD

// Raw workgroup barrier WITHOUT the vmcnt(0) drain __syncthreads() implies.
#define BAR_LDS() asm volatile("s_waitcnt lgkmcnt(0)\n\ts_barrier" ::: "memory")
#define WAIT_VM() asm volatile("s_waitcnt vmcnt(0)" ::: "memory")

typedef unsigned short ushort_t;
typedef __attribute__((ext_vector_type(8))) short short8;    // 8 bf16 = 4 VGPRs
typedef __attribute__((ext_vector_type(4))) float floatx4;   // MFMA C/D frag

#define MFMA __builtin_amdgcn_mfma_f32_16x16x32_bf16

// ---- workspace layout (floats) ----
#define WS_DEN   0
#define WS_LOSS  48
#define WS_CNT   49
#define WS_FRAGS 64
#define FR_F 0         // 256 frags: gates  [wcol:8][g:4][ks:8]  K=256 (c_c|m|h)
#define FR_A 256       // 16: W_td_h
#define FR_B 272       // 16: W_hist
#define FR_C 288       // 8 : W_feat masked
#define FR_E 296       // 16: W_comb
#define N_FRAGS 312
#define DENOM_BLOCKS (48 * 16)

__device__ __forceinline__ ushort_t f2bf(float x) {   // RNE float->bf16 bits
  unsigned int u = __float_as_uint(x);
  u += 0x7fffu + ((u >> 16) & 1u);
  return (ushort_t)(u >> 16);
}
__device__ __forceinline__ float sigmoidf_(float x) { return 1.0f / (1.0f + __expf(-x)); }
__device__ __forceinline__ float tanhf_(float x) { return 2.0f / (1.0f + __expf(-2.0f * x)) - 1.0f; }

// async global(16B/lane, per-lane addr) -> LDS(wave-uniform base + lane*16)
__device__ __forceinline__ void gload16(const float* g, const float* l) {
  __builtin_amdgcn_global_load_lds(
      (const __attribute__((address_space(1))) unsigned int*)(unsigned long long)(size_t)g,
      (__attribute__((address_space(3))) unsigned int*)(unsigned int)(size_t)l,
      16, 0, 0);
}

// ---------------- kernel 0: weight-frag packing + denom sums (verified R4-R6) ----------------
__global__ void prep_denom_kernel(const float* __restrict__ W_td_h, const float* __restrict__ W_hist,
                                  const float* __restrict__ W_feat, const float* __restrict__ W_comb,
                                  const float* __restrict__ W_ih, const float* __restrict__ W_hh,
                                  const float* __restrict__ masks, float* __restrict__ ws) {
  int tid = threadIdx.x;              // 256 threads
  if (blockIdx.x < N_FRAGS) {
    int f = blockIdx.x;
    ushort_t* fb = (ushort_t*)(ws + WS_FRAGS);
    #pragma unroll
    for (int u = 0; u < 2; u++) {
      int e = tid * 2 + u;            // 0..511 = l*8 + j
      int l = e >> 3, j = e & 7;
      int n16 = l & 15;
      int kq = ((l >> 4) << 3) + j;   // quad*8 + j
      float v;
      if (f < 256) {
        int w = f >> 5, g = (f >> 3) & 3, ks = f & 7;
        int n = g * 128 + w * 16 + n16;
        int k = ks * 32 + kq;
        v = (k < 128) ? W_ih[n * 128 + k] : W_hh[n * 128 + (k - 128)];
      } else if (f < 272) {
        int ff = f - 256, w = ff >> 1, ks = ff & 1;
        int n = w * 16 + n16;
        v = W_td_h[n * 64 + ks * 32 + kq];
      } else if (f < 288) {
        int ff = f - 272, w = ff >> 2, ks = ff & 3;
        int n = w * 16 + n16;
        v = W_hist[n * 128 + ks * 32 + kq];
      } else if (f < 296) {
        int ff = f - 288, w = ff >> 1, ks = ff & 1;
        int n = w * 16 + n16;
        int k = ks * 32 + kq;
        v = (n == k) ? 0.0f : W_feat[n * 64 + k];
      } else {
        int ff = f - 296, w = ff >> 2, ks = ff & 3;
        int n = w * 16 + n16;
        v = W_comb[n * 128 + ks * 32 + kq];
      }
      fb[f * 512 + e] = f2bf(v);
    }
  } else {
    int blk = blockIdx.x - N_FRAGS;
    int t = blk >> 4;
    int chunk = blk & 15;
    int base = chunk * 256;
    int j = tid & 63;
    int brow = tid >> 6;
    float s = 0.0f;
    for (int i = 0; i < 64; i++) {
      int b = base + i * 4 + brow;
      s += masks[((size_t)b * Tt + t) * Dd + j];
    }
    for (int off = 32; off > 0; off >>= 1) s += __shfl_down(s, off, 64);
    __shared__ float red[4];
    if ((tid & 63) == 0) red[tid >> 6] = s;
    __syncthreads();
    if (tid == 0) atomicAdd(&ws[WS_DEN + t], red[0] + red[1] + red[2] + red[3]);
  }
}

// ---------------- kernel 1: 16-wave gate-split recurrence, register-light ----------------
// Roles: wcol=w&7 (16 h-cols), gsel=w>>3 (gate pair: 0->{i,f}, 1->{g,o}).
// B + C + epilogues + loss on w8-11; E on w12-15; A + LSTM + h_dec on w0-7.
// Inputs stream via global_load_lds into dbl-buffered raw f32 LDS (waves 0-11 issue;
// own-wave vmcnt drain in P2, cross-wave visibility via the P2 barrier).
// Phases: P1 (issue loads; B/E + F.m/F.h; x_h/alpha epi) | P2 (C + c_c epi; WAIT_VM; store)
//       | P3a (F.c; gobuf export; format m/gamma_x/d for t+1) | P3b (A MFMA; LSTM; h_dec).
__global__ __launch_bounds__(NTHR)
void main_kernel(const float* __restrict__ values, const float* __restrict__ masks,
                 const float* __restrict__ deltas, const float* __restrict__ W_td_x,
                 const float* __restrict__ b_td_h, const float* __restrict__ b_td_x,
                 const float* __restrict__ b_hist, const float* __restrict__ b_feat,
                 const float* __restrict__ b_comb,
                 const float* __restrict__ b_ih, const float* __restrict__ b_hh,
                 float* ws, float* __restrict__ out) {
  __shared__ __align__(16) ushort_t act[16 * 264];    // bf16: c_c | m | h_dec
  __shared__ __align__(16) ushort_t dbuf[16 * 72];    // bf16 d(t+1)
  __shared__ __align__(16) ushort_t gxbuf[16 * 72];   // bf16 gamma_x
  __shared__ __align__(16) ushort_t xcbuf[16 * 72];   // bf16 x_c
  __shared__ __align__(16) float gobuf[2 * 16 * 132]; // fp32 g,o gate preacts
  __shared__ __align__(16) float albuf[16 * 68];      // fp32 alpha
  __shared__ __align__(16) float rawbuf[6144];        // fp32 [par:2][x,m,d][16*64] = 24 KB
  __shared__ __align__(16) ushort_t wstage[40 * 512]; // B(0-15) C(16-23) E(24-39) frags = 40 KB
  __shared__ float sden[48];
  __shared__ float dtxd[64], dtxb[64];                // W_td_x diag, b_td_x
  __shared__ float red[16];

  int tid = threadIdx.x;
  int w = tid >> 6, lane = tid & 63, l15 = lane & 15, quad = lane >> 4;
  int wcol = w & 7, gA = (w >> 3) * 2;
  int b0 = blockIdx.x * NB;
  const ushort_t* fb = (const ushort_t*)(ws + WS_FRAGS);

  for (int i = tid; i < 48; i += NTHR) sden[i] = 1.0f / (ws[WS_DEN + i] + 1e-5f);
  if (tid < 64) { dtxd[tid] = W_td_x[tid * 65]; dtxb[tid] = b_td_x[tid]; }
  for (int i = tid; i < 40 * 64; i += NTHR)
    *(short8*)(wstage + (size_t)i * 8) = *(const short8*)(fb + (size_t)FR_B * 512 + (size_t)i * 8);

  // per-wave F gate-pair frags: 16 = 64 regs
  short8 wF[16];
  #pragma unroll
  for (int g2 = 0; g2 < 2; g2++)
    #pragma unroll
    for (int ks = 0; ks < 8; ks++)
      wF[g2 * 8 + ks] =
          *(const short8*)(fb + (size_t)(FR_F + wcol * 32 + (gA + g2) * 8 + ks) * 512 + lane * 8);
  short8 wA0, wA1;
  if (w < 8) {
    wA0 = *(const short8*)(fb + (size_t)(FR_A + w * 2) * 512 + lane * 8);
    wA1 = *(const short8*)(fb + (size_t)(FR_A + w * 2 + 1) * 512 + lane * 8);
  }

  int colh = wcol * 16 + l15;
  float biasFa = b_ih[gA * 128 + colh] + b_hh[gA * 128 + colh];
  float biasFb = b_ih[(gA + 1) * 128 + colh] + b_hh[(gA + 1) * 128 + colh];
  float biasA = (w < 8) ? b_td_h[colh] : 0.0f;
  int colD = (w >= 12) ? (wcol - 4) * 16 + l15 : wcol * 16 + l15;
  float biasP = 0.0f, biasC = 0.0f;
  if (w >= 12) biasP = b_comb[colD];
  else if (w >= 8) { biasP = b_hist[colD]; biasC = b_feat[colD]; }

  const ushort_t* wbe_p =
      wstage + (size_t)((w < 12) ? wcol * 4 : 24 + (wcol - 4) * 4) * 512 + lane * 8;
  const ushort_t* wc_p = wstage + (size_t)(16 + wcol * 2) * 512 + lane * 8;

  int haB = quad * 4 * 264 + 128 + colh;
  long off0 = 1 + ((long)(b0 + quad * 4)) * Tt * Dd + colD;

  float c_reg[4] = {0.f, 0.f, 0.f, 0.f};
  float loss_acc = 0.0f;

  // ---- async input pipeline: waves 0-11 each own one (array, row-quad) chunk ----
  int arr = w >> 2, rq = w & 3;
  const float* gsrc = (arr == 0) ? values : (arr == 1) ? masks : deltas;
  const float* gp = gsrc + ((size_t)(b0 + rq * 4 + (lane >> 4)) * Tt) * Dd + (lane & 15) * 4;
  int rawoff = arr * 1024 + rq * 256;
  if (w < 12) { gload16(gp, rawbuf + rawoff); gp += Dd; }   // t=0 into parity 0

  // zero h_dec region [16][128]
  *(unsigned int*)(&act[(tid >> 6) * 264 + 128 + 2 * (tid & 63)]) = 0u;

  __syncthreads();   // drains each wave's vmcnt; raw t0 + wstage + dtx + sden visible

  {  // format t0: m -> act bf16, gamma_x -> gxbuf
    int row = tid >> 6, col = tid & 63;
    float mv = rawbuf[1024 + tid];
    float dv = rawbuf[2048 + tid];
    act[row * 264 + 64 + col] = f2bf(mv);
    gxbuf[row * 72 + col] = f2bf(__expf(-fmaxf(dv * dtxd[col] + dtxb[col], 0.0f)));
  }
  BAR_LDS();

  for (int t = 0; t < Tt; t++) {
    int cur3 = (t & 1) * 3072, nx3 = 3072 - cur3;
    floatx4 aA = {biasFa, biasFa, biasFa, biasFa};
    floatx4 aB = {biasFb, biasFb, biasFb, biasFb};
    floatx4 accP = {biasP, biasP, biasP, biasP};

    // ---- P1: issue t+1 loads; B (8-11) / E (12-15); F.m + F.h (all); epilogues ----
    if (w < 12 && t + 1 < Tt) {
      gload16(gp, rawbuf + nx3 + rawoff);
      gp += Dd;
    }
    short8 mf0 = *(const short8*)(&act[l15 * 264 + 64 + quad * 8]);
    short8 mf1 = *(const short8*)(&act[l15 * 264 + 96 + quad * 8]);
    short8 hf0 = *(const short8*)(&act[l15 * 264 + 128 + quad * 8]);
    short8 hf1 = *(const short8*)(&act[l15 * 264 + 160 + quad * 8]);
    short8 hf2 = *(const short8*)(&act[l15 * 264 + 192 + quad * 8]);
    short8 hf3 = *(const short8*)(&act[l15 * 264 + 224 + quad * 8]);
    if (w >= 8) {
      short8 wb0 = *(const short8*)(wbe_p);
      short8 wb1 = *(const short8*)(wbe_p + 512);
      short8 wb2 = *(const short8*)(wbe_p + 1024);
      short8 wb3 = *(const short8*)(wbe_p + 1536);
      if (w < 12) {                                   // B: x_h
        accP = MFMA(hf0, wb0, accP, 0, 0, 0);
        accP = MFMA(hf1, wb1, accP, 0, 0, 0);
        accP = MFMA(hf2, wb2, accP, 0, 0, 0);
        accP = MFMA(hf3, wb3, accP, 0, 0, 0);
      } else {                                        // E: alpha
        short8 gx0 = *(const short8*)(&gxbuf[l15 * 72 + quad * 8]);
        short8 gx1 = *(const short8*)(&gxbuf[l15 * 72 + 32 + quad * 8]);
        accP = MFMA(gx0, wb0, accP, 0, 0, 0);
        accP = MFMA(gx1, wb1, accP, 0, 0, 0);
        accP = MFMA(mf0, wb2, accP, 0, 0, 0);
        accP = MFMA(mf1, wb3, accP, 0, 0, 0);
      }
    }
    aA = MFMA(mf0, wF[2],  aA, 0, 0, 0);
    aA = MFMA(mf1, wF[3],  aA, 0, 0, 0);
    aB = MFMA(mf0, wF[10], aB, 0, 0, 0);
    aB = MFMA(mf1, wF[11], aB, 0, 0, 0);
    aA = MFMA(hf0, wF[4],  aA, 0, 0, 0);
    aA = MFMA(hf1, wF[5],  aA, 0, 0, 0);
    aA = MFMA(hf2, wF[6],  aA, 0, 0, 0);
    aA = MFMA(hf3, wF[7],  aA, 0, 0, 0);
    aB = MFMA(hf0, wF[12], aB, 0, 0, 0);
    aB = MFMA(hf1, wF[13], aB, 0, 0, 0);
    aB = MFMA(hf2, wF[14], aB, 0, 0, 0);
    aB = MFMA(hf3, wF[15], aB, 0, 0, 0);
    if (w >= 8 && w < 12) {                            // x_h epilogue: loss1, x_c
      float invden = sden[t];
      float s1 = 0.0f;
      #pragma unroll
      for (int r = 0; r < 4; r++) {
        int m = quad * 4 + r;
        float xv = rawbuf[cur3 + m * 64 + colD];
        float mv = rawbuf[cur3 + 1024 + m * 64 + colD];
        float xh = accP[r];
        s1 += fabsf(xv - xh) * mv;
        xcbuf[m * 72 + colD] = f2bf(mv * xv + (1.0f - mv) * xh);
      }
      loss_acc += s1 * invden;
    } else if (w >= 12) {
      #pragma unroll
      for (int r = 0; r < 4; r++)
        albuf[(quad * 4 + r) * 68 + colD] = accP[r];
    }
    BAR_LDS();                                         // x_c + alpha staged

    // ---- P2: C + c_c epilogue (8-11); own-wave vmcnt drain; stores ----
    float cc0 = 0.f, cc1 = 0.f, cc2 = 0.f, cc3 = 0.f;
    if (w >= 8 && w < 12) {
      short8 xc0 = *(const short8*)(&xcbuf[l15 * 72 + quad * 8]);
      short8 xc1 = *(const short8*)(&xcbuf[l15 * 72 + 32 + quad * 8]);
      short8 wc0 = *(const short8*)(wc_p);
      short8 wc1 = *(const short8*)(wc_p + 512);
      floatx4 accC = {biasC, biasC, biasC, biasC};
      accC = MFMA(xc0, wc0, accC, 0, 0, 0);
      accC = MFMA(xc1, wc1, accC, 0, 0, 0);
      float invden = sden[t];
      float s23 = 0.0f;
      float ccs[4];
      #pragma unroll
      for (int r = 0; r < 4; r++) {
        int m = quad * 4 + r;
        float xv = rawbuf[cur3 + m * 64 + colD];
        float mv = rawbuf[cur3 + 1024 + m * 64 + colD];
        float xh = accP[r];
        float zh = accC[r];
        float al = albuf[m * 68 + colD];
        s23 += fabsf(xv - zh) * mv;                    // loss2
        float ch = al * zh + (1.0f - al) * xh;
        s23 += fabsf(xv - ch) * mv;                    // loss3
        float cc = mv * xv + (1.0f - mv) * ch;
        ccs[r] = cc;
        act[m * 264 + colD] = f2bf(cc);
      }
      loss_acc += s23 * invden;
      cc0 = ccs[0]; cc1 = ccs[1]; cc2 = ccs[2]; cc3 = ccs[3];
    }
    WAIT_VM();                                         // own gloads for t+1 landed in LDS
    if (w >= 8 && w < 12) {                            // stores after wait: never drained later
      int tofs = t * Dd;
      out[off0 + tofs] = cc0;
      out[off0 + 3072 + tofs] = cc1;
      out[off0 + 6144 + tofs] = cc2;
      out[off0 + 9216 + tofs] = cc3;
    }
    BAR_LDS();                                         // c_c staged; raw[nxt] visible to ALL waves

    // ---- P3a: F.c (all); gobuf export (8-15); format t+1 inputs (all) ----
    short8 cf0 = *(const short8*)(&act[l15 * 264 + quad * 8]);
    short8 cf1 = *(const short8*)(&act[l15 * 264 + 32 + quad * 8]);
    aA = MFMA(cf0, wF[0], aA, 0, 0, 0);
    aA = MFMA(cf1, wF[1], aA, 0, 0, 0);
    aB = MFMA(cf0, wF[8], aB, 0, 0, 0);
    aB = MFMA(cf1, wF[9], aB, 0, 0, 0);
    if (w >= 8) {
      #pragma unroll
      for (int r = 0; r < 4; r++) {                    // export g,o preacts
        int m = quad * 4 + r;
        gobuf[m * 132 + colh] = aA[r];
        gobuf[2112 + m * 132 + colh] = aB[r];
      }
    }
    {   // format t+1: m -> act bf16, gamma_x -> gxbuf, d -> dbuf (1 elem/thread)
      int row = tid >> 6, col = tid & 63;
      float mv = rawbuf[nx3 + 1024 + tid];
      float dv = rawbuf[nx3 + 2048 + tid];
      act[row * 264 + 64 + col] = f2bf(mv);
      gxbuf[row * 72 + col] = f2bf(__expf(-fmaxf(dv * dtxd[col] + dtxb[col], 0.0f)));
      dbuf[row * 72 + col] = f2bf(dv);
    }
    BAR_LDS();                                         // gobuf + t+1 inputs staged

    // ---- P3b: A MFMA -> gamma_h(t+1); LSTM; h_dec(t+1) (waves 0-7) ----
    if (w < 8) {
      short8 df0 = *(const short8*)(&dbuf[l15 * 72 + quad * 8]);
      short8 df1 = *(const short8*)(&dbuf[l15 * 72 + 32 + quad * 8]);
      floatx4 accA = {biasA, biasA, biasA, biasA};
      accA = MFMA(df0, wA0, accA, 0, 0, 0);
      accA = MFMA(df1, wA1, accA, 0, 0, 0);
      #pragma unroll
      for (int r = 0; r < 4; r++) {
        int m = quad * 4 + r;
        float gg = gobuf[m * 132 + colh];
        float og = gobuf[2112 + m * 132 + colh];
        float ig = sigmoidf_(aA[r]);                   // gate i
        float fg = sigmoidf_(aB[r]);                   // gate f
        float g_ = tanhf_(gg);
        float o_ = sigmoidf_(og);
        c_reg[r] = fg * c_reg[r] + ig * g_;
        float h_ = o_ * tanhf_(c_reg[r]);
        float hd = h_ * __expf(-fmaxf(accA[r], 0.0f)); // h_dec(t+1)
        act[haB + r * 264] = f2bf(hd);
      }
    }
    BAR_LDS();                                         // h_dec staged
  }

  // ---- loss reduction + folded finalization ----
  float s = loss_acc;
  for (int off = 32; off > 0; off >>= 1) s += __shfl_down(s, off, 64);
  if (lane == 0) red[w] = s;
  __syncthreads();
  if (tid == 0) {
    float tot = 0.0f;
    #pragma unroll
    for (int i = 0; i < 16; i++) tot += red[i];
    atomicAdd(&ws[WS_LOSS], tot);
    __threadfence();
    unsigned int done = atomicAdd((unsigned int*)&ws[WS_CNT], 1u);
    if (done == (unsigned int)(gridDim.x - 1)) {
      float lv = atomicAdd(&ws[WS_LOSS], 0.0f);
      out[0] = 0.3f * lv;
    }
  }
}

extern "C" void kernel_launch(void* const* d_in, const int* in_sizes, int n_in,
                              void* d_out, int out_size, void* d_ws, size_t ws_size,
                              hipStream_t stream) {
  const float* values = (const float*)d_in[0];
  const float* masks  = (const float*)d_in[1];
  const float* deltas = (const float*)d_in[2];
  const float* W_td_h = (const float*)d_in[3];
  const float* b_td_h = (const float*)d_in[4];
  const float* W_td_x = (const float*)d_in[5];
  const float* b_td_x = (const float*)d_in[6];
  const float* W_hist = (const float*)d_in[7];
  const float* b_hist = (const float*)d_in[8];
  const float* W_feat = (const float*)d_in[9];
  const float* b_feat = (const float*)d_in[10];
  const float* W_comb = (const float*)d_in[11];
  const float* b_comb = (const float*)d_in[12];
  const float* W_ih   = (const float*)d_in[13];
  const float* W_hh   = (const float*)d_in[14];
  const float* b_ih   = (const float*)d_in[15];
  const float* b_hh   = (const float*)d_in[16];
  float* out = (float*)d_out;
  float* ws  = (float*)d_ws;   // uses 64 + 312*256 floats ≈ 320 KB

  hipMemsetAsync(ws, 0, 64 * sizeof(float), stream);
  prep_denom_kernel<<<dim3(N_FRAGS + DENOM_BLOCKS), dim3(256), 0, stream>>>(
      W_td_h, W_hist, W_feat, W_comb, W_ih, W_hh, masks, ws);
  main_kernel<<<dim3(Bb / NB), dim3(NTHR), 0, stream>>>(values, masks, deltas, W_td_x,
                                                        b_td_h, b_td_x, b_hist, b_feat,
                                                        b_comb, b_ih, b_hh, ws, out);
}